// Round 2
// baseline (19605.324 us; speedup 1.0000x reference)
//
#include <hip/hip_runtime.h>

#define NELEM     16777216   // 64^4
#define CI_STRIDE 262144     // 64^3
#define WTP_PASS  36864      // 64ci * 3 * 3 * 64co
#define NFLAG     (6 * 256 * 16)

__device__ float    g_bufA[NELEM + 32];
__device__ float    g_bufB[NELEM + 32];
__device__ float    g_wtp[6 * WTP_PASS];
__device__ unsigned g_flags[NFLAG];

// Weight prep: g_wtp[p][((ci*3+ky)*3+kx)*64+co]; passes 4,5 spatially transposed.
// Also zeroes all sync flags (runs before every pass in the graph).
__global__ __launch_bounds__(256) void prep(
    const float* __restrict__ w0, const float* __restrict__ w1,
    const float* __restrict__ w2, const float* __restrict__ w3,
    const float* __restrict__ w4, const float* __restrict__ w5)
{
    int gid = blockIdx.x * 256 + threadIdx.x;
    if (gid < NFLAG) g_flags[gid] = 0;
    if (gid >= 6 * WTP_PASS) return;
    int p  = gid / WTP_PASS;
    int r  = gid % WTP_PASS;
    int co = r & 63;
    int q  = r >> 6;          // ci*9 + ky*3 + kx
    int kx = q % 3;
    int t2 = q / 3;
    int ky = t2 % 3;
    int ci = t2 / 3;
    const float* src = (p==0)?w0:(p==1)?w1:(p==2)?w2:(p==3)?w3:(p==4)?w4:w5;
    g_wtp[gid] = (p < 4) ? src[co*576 + ci*9 + ky*3 + kx]
                         : src[co*576 + ci*9 + kx*3 + ky];
}

// Swap last two dims: in[o][a][b] -> out[o][b][a], o in [0,4096), a,b = 64
__global__ __launch_bounds__(256) void transpose_hw(
    const float* __restrict__ in, float* __restrict__ out)
{
    __shared__ float t[64][65];
    const size_t base = (size_t)blockIdx.x * 4096;
    const int c  = threadIdx.x & 63;
    const int r4 = threadIdx.x >> 6;
#pragma unroll
    for (int r = 0; r < 16; ++r) {
        int a = r4 * 16 + r;
        t[a][c] = in[base + a * 64 + c];
    }
    __syncthreads();
#pragma unroll
    for (int r = 0; r < 16; ++r) {
        int bb = r4 * 16 + r;
        out[base + (size_t)bb * 64 + c] = t[c][bb];
    }
}

// Persistent per-pass scan kernel. Block = 4x4 px tile x 64 co; wave = 16-ci
// chunk (lane = co, weights in VGPRs). Neighbor-flag sync per step.
__global__ __launch_bounds__(256, 1) void pass_kernel(
    float* __restrict__ buf, const float* __restrict__ wtp,
    unsigned* __restrict__ flags, int st, int su, int dir)
{
    __shared__ float red[21504];   // 84 KB -> exactly 1 block/CU (occupancy cap)
    const int tid  = threadIdx.x;
    const int lane = tid & 63;
    const int wv   = tid >> 6;
    const int b    = blockIdx.x;
    const int bu   = b >> 4, bv = b & 15;
    const int u0   = bu << 2, v0 = bv << 2;

    // per-lane weights for this wave's 16 ci (loaded once per pass)
    float W[16][3][3];
#pragma unroll
    for (int i = 0; i < 16; ++i)
#pragma unroll
        for (int ky = 0; ky < 3; ++ky)
#pragma unroll
            for (int kx = 0; kx < 3; ++kx)
                W[i][ky][kx] = wtp[(((wv*16 + i)*3 + ky)*3 + kx)*64 + lane];

    // lanes 0..7 of wave 0 each own one spatial neighbor's flag
    int nbr = -1;
    if (lane < 8) {
        int c  = lane + (lane >= 4 ? 1 : 0);   // skip center of 3x3
        int nu = bu + c/3 - 1, nv = bv + c%3 - 1;
        if (nu >= 0 && nu < 16 && nv >= 0 && nv < 16) nbr = (nu*16 + nv)*16;
    }

    for (int s = 1; s <= 63; ++s) {
        const int t  = (dir > 0) ? s : 63 - s;
        const int tp = t - dir;

        // wait until all neighbors have completed step s-1
        if (wv == 0 && s > 1) {
            const unsigned tgt = (unsigned)(s - 1);
            bool ok = (nbr < 0);
            int spins = 0;
            while (!__all(ok) && spins < (1 << 24)) {
                if (!ok) ok = __hip_atomic_load(&flags[nbr], __ATOMIC_RELAXED,
                                                __HIP_MEMORY_SCOPE_AGENT) >= tgt;
                ++spins;
            }
            __threadfence();   // acquire: invalidate L1/L2 so halo reads are fresh
        }
        __syncthreads();

        const float* prev = buf + (size_t)tp * st;
        float acc[4][4] = {{0.f}};
#pragma unroll
        for (int i = 0; i < 16; ++i) {
            const float* cb = prev + (size_t)(wv*16 + i) * CI_STRIDE;
            float win[6][6];
#pragma unroll
            for (int r = 0; r < 6; ++r) {
                const int uu = u0 - 1 + r;
                if (uu >= 0 && uu <= 63) {
                    const float* rp = cb + (size_t)uu * su + v0;
                    float4 m = *(const float4*)rp;              // 16B aligned
                    win[r][0] = (v0 != 0)  ? rp[-1] : 0.f;      // zero padding
                    win[r][5] = (v0 != 60) ? rp[4]  : 0.f;
                    win[r][1] = m.x; win[r][2] = m.y; win[r][3] = m.z; win[r][4] = m.w;
                } else {
                    win[r][0]=win[r][1]=win[r][2]=win[r][3]=win[r][4]=win[r][5]=0.f;
                }
            }
#pragma unroll
            for (int oi = 0; oi < 4; ++oi)
#pragma unroll
                for (int ky = 0; ky < 3; ++ky) {
                    const float k0 = W[i][ky][0], k1 = W[i][ky][1], k2 = W[i][ky][2];
#pragma unroll
                    for (int oj = 0; oj < 4; ++oj)
                        acc[oi][oj] = fmaf(win[oi+ky][oj],   k0,
                                      fmaf(win[oi+ky][oj+1], k1,
                                      fmaf(win[oi+ky][oj+2], k2, acc[oi][oj])));
                }
        }

        // cross-wave ci-reduction via LDS
#pragma unroll
        for (int oi = 0; oi < 4; ++oi)
#pragma unroll
            for (int oj = 0; oj < 4; ++oj)
                red[(wv*16 + oi*4 + oj)*64 + lane] = acc[oi][oj];
        __syncthreads();

        float s0=0.f, s1=0.f, s2=0.f, s3=0.f;
#pragma unroll
        for (int j2 = 0; j2 < 4; ++j2) {
            s0 += red[(j2*16 + wv*4 + 0)*64 + lane];
            s1 += red[(j2*16 + wv*4 + 1)*64 + lane];
            s2 += red[(j2*16 + wv*4 + 2)*64 + lane];
            s3 += red[(j2*16 + wv*4 + 3)*64 + lane];
        }
        // wave wv owns output row u0+wv, cols v0..v0+3 (contiguous -> float4 RMW)
        float* cp = buf + (size_t)t*st + (size_t)lane*CI_STRIDE
                  + (size_t)(u0+wv)*su + v0;
        float4 c = *(float4*)cp;
        c.x += fmaxf(s0, 0.f); c.y += fmaxf(s1, 0.f);
        c.z += fmaxf(s2, 0.f); c.w += fmaxf(s3, 0.f);
        *(float4*)cp = c;
        __syncthreads();   // drains all waves' stores (vmcnt) before publish

        if (tid == 0) {
            __threadfence();   // release: write back L2 so other XCDs see the tile
            __hip_atomic_store(&flags[b*16], (unsigned)s, __ATOMIC_RELAXED,
                               __HIP_MEMORY_SCOPE_AGENT);
        }
    }
}

extern "C" void kernel_launch(void* const* d_in, const int* in_sizes, int n_in,
                              void* d_out, int out_size, void* d_ws, size_t ws_size,
                              hipStream_t stream)
{
    (void)in_sizes; (void)n_in; (void)out_size; (void)d_ws; (void)ws_size;
    const float* x = (const float*)d_in[0];
    float* out = (float*)d_out;

    void *pa, *pb, *pw, *pf;
    hipGetSymbolAddress(&pa, HIP_SYMBOL(g_bufA));
    hipGetSymbolAddress(&pb, HIP_SYMBOL(g_bufB));
    hipGetSymbolAddress(&pw, HIP_SYMBOL(g_wtp));
    hipGetSymbolAddress(&pf, HIP_SYMBOL(g_flags));
    float* A = (float*)pa + 16;   // +16 pad so col -1 loads stay in-buffer
    float* B = (float*)pb + 16;
    float* wtp = (float*)pw;
    unsigned* flags = (unsigned*)pf;

    prep<<<864, 256, 0, stream>>>(
        (const float*)d_in[1], (const float*)d_in[2], (const float*)d_in[3],
        (const float*)d_in[4], (const float*)d_in[5], (const float*)d_in[6]);

    hipMemcpyAsync(A, x, (size_t)NELEM * sizeof(float),
                   hipMemcpyDeviceToDevice, stream);

    // layout0 [k][d][h][w]: passes UD/DU: t=h (st 64), u=d (su 4096), v=w
    pass_kernel<<<256, 256, 0, stream>>>(A, wtp + 0*WTP_PASS, flags + 0*4096, 64, 4096, +1);
    pass_kernel<<<256, 256, 0, stream>>>(A, wtp + 1*WTP_PASS, flags + 1*4096, 64, 4096, -1);

    transpose_hw<<<4096, 256, 0, stream>>>(A, B);   // -> layout1 [k][d][w][h]

    // LR/RL: t=w (st 64), u=d (su 4096), v=h
    pass_kernel<<<256, 256, 0, stream>>>(B, wtp + 2*WTP_PASS, flags + 2*4096, 64, 4096, +1);
    pass_kernel<<<256, 256, 0, stream>>>(B, wtp + 3*WTP_PASS, flags + 3*4096, 64, 4096, -1);
    // FB/BF: t=d (st 4096), u=w (su 64), v=h; weights spatially transposed in prep
    pass_kernel<<<256, 256, 0, stream>>>(B, wtp + 4*WTP_PASS, flags + 4*4096, 4096, 64, +1);
    pass_kernel<<<256, 256, 0, stream>>>(B, wtp + 5*WTP_PASS, flags + 5*4096, 4096, 64, -1);

    transpose_hw<<<4096, 256, 0, stream>>>(B, out);
}